// Round 1
// baseline (74.297 us; speedup 1.0000x reference)
//
#include <hip/hip_runtime.h>
#include <hip/hip_bf16.h>
#include <math.h>

#define EMBED  128
#define NUM_C  64
#define EPS    1e-5f
#define NPB    32            // nodes per block tile

typedef __attribute__((ext_vector_type(8))) short bf16x8;   // MFMA A/B frag
typedef __attribute__((ext_vector_type(4))) float f32x4;    // MFMA C/D frag

__device__ __forceinline__ bf16x8 pack8(float4 x, float4 y) {
    __hip_bfloat162 p0 = __float22bfloat162_rn(float2{x.x, x.y});
    __hip_bfloat162 p1 = __float22bfloat162_rn(float2{x.z, x.w});
    __hip_bfloat162 p2 = __float22bfloat162_rn(float2{y.x, y.y});
    __hip_bfloat162 p3 = __float22bfloat162_rn(float2{y.z, y.w});
    union { __hip_bfloat162 h[4]; bf16x8 v; } u;
    u.h[0] = p0; u.h[1] = p1; u.h[2] = p2; u.h[3] = p3;
    return u.v;
}

// R11: operand-swapped, LDS-free, barrier-free main kernel.
//   A = centroid frags (rows = cents), B = node frags (cols = nodes).
//   Fragment layout is symmetric (lane lm holds row/col lm, k-slice quad*8),
//   so node k-slices load DIRECTLY from row-major global -> no LDS staging,
//   no __syncthreads, and D gives each lane 4 CONSECUTIVE centroids of one
//   node -> global_store_dwordx4 (2 stores/lane instead of 8 scalar).
// Carried post-mortems:
//   R7:  cooperative grid.sync ~= +60us on this harness -- never.
//   R9:  per-block __threadfence (buffer_wbl2 storm) ~= +20us.
//   R10: fence-free last-block atomic protocol +6us vs 2-kernel reduce
//        (keep transposed-workspace + cd_fin1 protocol).
// R11 prediction: cd_main ~26us -> 10-15us (no barrier drain, no LDS
//   round-trip, 4x fewer store instrs); total 71.5 -> ~56-62us.
__global__ __launch_bounds__(256) void cd_main(
    const float* __restrict__ node_repr,   // [N,128]
    const float* __restrict__ mask,        // [N,1]
    const float* __restrict__ cent,        // [64,128]
    float* __restrict__ out,               // [64 + N*64]
    float* __restrict__ wcol,              // [64][nb] transposed column partials
    float* __restrict__ wmsk,              // [nb] mask partials
    int N, int nb, int atomicMode)
{
    const int tid  = threadIdx.x;
    const int lane = tid & 63;
    const int wv   = tid >> 6;
    const int quad = lane >> 4;            // 0..3 (k-slice group)
    const int lm   = lane & 15;            // A row (cent) / B col (node)
    const int cw   = wv * 16;              // wave's centroid group base
    const int node0 = blockIdx.x * NPB;

    // ---- A (centroids): load + fp32 norm + bf16 pack; rows cw..cw+15 ----
    const float* ap = cent + (long)(cw + lm) * EMBED + quad * 8;
    float svp = 0.f;
    bf16x8 aa[4];
    #pragma unroll
    for (int ks = 0; ks < 4; ++ks) {
        float4 a0 = *(const float4*)(ap + ks * 32);
        float4 a1 = *(const float4*)(ap + ks * 32 + 4);
        svp = fmaf(a0.x,a0.x, fmaf(a0.y,a0.y, fmaf(a0.z,a0.z, fmaf(a0.w,a0.w, svp))));
        svp = fmaf(a1.x,a1.x, fmaf(a1.y,a1.y, fmaf(a1.z,a1.z, fmaf(a1.w,a1.w, svp))));
        aa[ks] = pack8(a0, a1);
    }
    svp += __shfl_xor(svp, 16); svp += __shfl_xor(svp, 32);   // full ||c||^2, cent cw+lm
    // redistribute cent norms to D-row mapping: lane needs cents cw+quad*4+r
    float svr[4], sv1r[4];
    #pragma unroll
    for (int r = 0; r < 4; ++r) {
        svr[r]  = __shfl(svp, quad * 4 + r);   // held by lane (quad0, lm=quad*4+r)
        sv1r[r] = 1.f - svr[r];
    }

    // ---- B (nodes): lane owns node lm (and lm+16), k-slice quad*8+ks*32 ----
    const int n0 = node0 + lm;
    const int n1 = node0 + 16 + lm;
    const int c0 = (n0 < N) ? n0 : N - 1;
    const int c1 = (n1 < N) ? n1 : N - 1;
    const float* p0 = node_repr + (long)c0 * EMBED + quad * 8;
    const float* p1 = node_repr + (long)c1 * EMBED + quad * 8;
    float su0 = 0.f, su1 = 0.f;
    bf16x8 b0[4], b1[4];
    #pragma unroll
    for (int ks = 0; ks < 4; ++ks) {
        float4 x0 = *(const float4*)(p0 + ks * 32);
        float4 x1 = *(const float4*)(p0 + ks * 32 + 4);
        float4 y0 = *(const float4*)(p1 + ks * 32);
        float4 y1 = *(const float4*)(p1 + ks * 32 + 4);
        su0 = fmaf(x0.x,x0.x, fmaf(x0.y,x0.y, fmaf(x0.z,x0.z, fmaf(x0.w,x0.w, su0))));
        su0 = fmaf(x1.x,x1.x, fmaf(x1.y,x1.y, fmaf(x1.z,x1.z, fmaf(x1.w,x1.w, su0))));
        su1 = fmaf(y0.x,y0.x, fmaf(y0.y,y0.y, fmaf(y0.z,y0.z, fmaf(y0.w,y0.w, su1))));
        su1 = fmaf(y1.x,y1.x, fmaf(y1.y,y1.y, fmaf(y1.z,y1.z, fmaf(y1.w,y1.w, su1))));
        b0[ks] = pack8(x0, x1);
        b1[ks] = pack8(y0, y1);
    }
    su0 += __shfl_xor(su0, 16); su0 += __shfl_xor(su0, 32);   // full ||u||^2, node n0
    su1 += __shfl_xor(su1, 16); su1 += __shfl_xor(su1, 32);   // full ||u||^2, node n1
    const float mk0 = (n0 < N) ? mask[c0] : 0.f;
    const float mk1 = (n1 < N) ? mask[c1] : 0.f;

    // ---- MFMA: cent x node, 2 node-halves x 4 k-steps, all from registers ----
    f32x4 acc0 = {0.f,0.f,0.f,0.f}, acc1 = {0.f,0.f,0.f,0.f};
    #pragma unroll
    for (int ks = 0; ks < 4; ++ks) {
        acc0 = __builtin_amdgcn_mfma_f32_16x16x32_bf16(aa[ks], b0[ks], acc0, 0, 0, 0);
        acc1 = __builtin_amdgcn_mfma_f32_16x16x32_bf16(aa[ks], b1[ks], acc1, 0, 0, 0);
    }

    // ---- epilogue: D row = cent quad*4+r, col = node lm ----
    const float o0 = 1.f - su0, o1 = 1.f - su1;
    float v0a[4], v1a[4], g[4];
    #pragma unroll
    for (int r = 0; r < 4; ++r) {
        {
            float sq = fmaxf(su0 + svr[r] - 2.f * acc0[r], 0.f);
            float dn = fmaxf(o0 * sv1r[r], EPS);
            float tt = fmaxf(2.f * sq * __builtin_amdgcn_rcpf(dn), EPS);
            v0a[r] = __logf(1.f + tt + sqrtf(tt * (tt + 2.f))) * mk0;
        }
        {
            float sq = fmaxf(su1 + svr[r] - 2.f * acc1[r], 0.f);
            float dn = fmaxf(o1 * sv1r[r], EPS);
            float tt = fmaxf(2.f * sq * __builtin_amdgcn_rcpf(dn), EPS);
            v1a[r] = __logf(1.f + tt + sqrtf(tt * (tt + 2.f))) * mk1;
        }
        g[r] = v0a[r] + v1a[r];
    }
    // vector stores: 4 consecutive cents per lane, 16B aligned
    if (n0 < N) {
        float4 V0 = {v0a[0], v0a[1], v0a[2], v0a[3]};
        *(float4*)(out + NUM_C + (long)n0 * NUM_C + cw + quad * 4) = V0;
    }
    if (n1 < N) {
        float4 V1 = {v1a[0], v1a[1], v1a[2], v1a[3]};
        *(float4*)(out + NUM_C + (long)n1 * NUM_C + cw + quad * 4) = V1;
    }

    // ---- per-cent column sums over this tile's 32 nodes (in-quad reduce) ----
    #pragma unroll
    for (int r = 0; r < 4; ++r) {
        g[r] += __shfl_xor(g[r], 1);
        g[r] += __shfl_xor(g[r], 2);
        g[r] += __shfl_xor(g[r], 4);
        g[r] += __shfl_xor(g[r], 8);
    }
    if (lm == 0) {
        if (atomicMode) {
            #pragma unroll
            for (int r = 0; r < 4; ++r) atomicAdd(&wcol[cw + quad * 4 + r], g[r]);
        } else {
            #pragma unroll
            for (int r = 0; r < 4; ++r)
                wcol[(long)(cw + quad * 4 + r) * nb + blockIdx.x] = g[r];
        }
    }

    // ---- block mask partial (wave 0, quad 0 holds all 32 node masks) ----
    if (wv == 0) {
        float ms = mk0 + mk1;
        ms += __shfl_xor(ms, 1); ms += __shfl_xor(ms, 2);
        ms += __shfl_xor(ms, 4); ms += __shfl_xor(ms, 8);
        if (lane == 0) {
            if (atomicMode) atomicAdd(&wmsk[0], ms);
            else            wmsk[blockIdx.x] = ms;
        }
    }
}

// Reduce: 64 blocks; block c sums its contiguous column + (redundantly) mask.
__global__ __launch_bounds__(256) void cd_fin1(
    const float* __restrict__ wcol, const float* __restrict__ wmsk,
    float* __restrict__ out, int nb)
{
    __shared__ float rs[4], rm[4];
    const int c   = blockIdx.x;
    const int tid = threadIdx.x;

    float s = 0.f, m = 0.f;
    for (int b = tid; b < nb; b += 256) {
        s += wcol[(long)c * nb + b];        // coalesced: contiguous column
        m += wmsk[b];
    }
    #pragma unroll
    for (int k = 32; k; k >>= 1) { s += __shfl_xor(s, k, 64); m += __shfl_xor(m, k, 64); }
    if ((tid & 63) == 0) { rs[tid >> 6] = s; rm[tid >> 6] = m; }
    __syncthreads();
    if (tid == 0)
        out[c] = (rs[0] + rs[1] + rs[2] + rs[3]) / (rm[0] + rm[1] + rm[2] + rm[3]);
}

// atomic-mode fallback helpers
__global__ void cd_zero(float* acc) { if (threadIdx.x < NUM_C + 1) acc[threadIdx.x] = 0.f; }
__global__ void cd_fin_atomic(const float* __restrict__ acc, float* __restrict__ out) {
    int c = threadIdx.x;
    if (c < NUM_C) out[c] = acc[c] / acc[NUM_C];
}

extern "C" void kernel_launch(void* const* d_in, const int* in_sizes, int n_in,
                              void* d_out, int out_size, void* d_ws, size_t ws_size,
                              hipStream_t stream) {
    const float* node_repr = (const float*)d_in[0];
    const float* mask      = (const float*)d_in[1];
    const float* cent      = (const float*)d_in[2];
    float* out = (float*)d_out;

    const int N  = in_sizes[0] / EMBED;
    const int nb = (N + NPB - 1) / NPB;
    const size_t needed = ((size_t)NUM_C * nb + nb) * sizeof(float);

    if (ws_size >= needed) {
        float* wcol = (float*)d_ws;                  // [64][nb] transposed
        float* wmsk = wcol + (size_t)NUM_C * nb;     // [nb]
        cd_main<<<nb, 256, 0, stream>>>(node_repr, mask, cent, out, wcol, wmsk, N, nb, 0);
        cd_fin1<<<NUM_C, 256, 0, stream>>>(wcol, wmsk, out, nb);
    } else {
        float* acc = (float*)d_ws;   // 65 floats
        cd_zero<<<1, 128, 0, stream>>>(acc);
        cd_main<<<nb, 256, 0, stream>>>(node_repr, mask, cent, out, acc, acc + NUM_C, N, nb, 1);
        cd_fin_atomic<<<1, 64, 0, stream>>>(acc, out);
    }
}

// Round 2
// 71.431 us; speedup vs baseline: 1.0401x; 1.0401x over previous
//
#include <hip/hip_runtime.h>
#include <hip/hip_bf16.h>
#include <math.h>

#define EMBED  128
#define NUM_C  64
#define EPS    1e-5f
#define NPB    32            // nodes per block (one tile per block)
#define LDSROW 132           // floats; padded rows, bank-balanced b128 pattern

typedef __attribute__((ext_vector_type(8))) short bf16x8;   // MFMA A/B frag
typedef __attribute__((ext_vector_type(4))) float f32x4;    // MFMA C/D frag

__device__ __forceinline__ bf16x8 pack8(float4 x, float4 y) {
    __hip_bfloat162 p0 = __float22bfloat162_rn(float2{x.x, x.y});
    __hip_bfloat162 p1 = __float22bfloat162_rn(float2{x.z, x.w});
    __hip_bfloat162 p2 = __float22bfloat162_rn(float2{y.x, y.y});
    __hip_bfloat162 p3 = __float22bfloat162_rn(float2{y.z, y.w});
    union { __hip_bfloat162 h[4]; bf16x8 v; } u;
    u.h[0] = p0; u.h[1] = p1; u.h[2] = p2; u.h[3] = p3;
    return u.v;
}

// R12 hybrid: R10's coalesced LDS staging + single barrier (proven) combined
// with R11's operand swap (A=cent, B=node) so D gives each lane 4 CONSECUTIVE
// centroids of one node -> 2x global_store_dwordx4 instead of 8 scalar stores,
// and su/ms become 2 broadcast LDS reads instead of 8 per-m0 reads.
// Post-mortems encoded here:
//   R7:  cooperative grid.sync ~= +60us on this harness -- never.
//   R9:  per-block __threadfence (buffer_wbl2 storm) ~= +20us.
//   R10: fence-free last-block atomic protocol +6us vs 2-kernel reduce.
//   R11: barrier-free scattered per-lane node loads = +2.8us (uncoalesced
//        512B-stride 16B loads + 4x wave duplication beat the barrier cost).
// R12 prediction: 67-71us; if it lands back in the 71-74 band, three
// structures measure identical -> remaining ~30us is fill+launch floor.
__global__ __launch_bounds__(256) void cd_main(
    const float* __restrict__ node_repr,   // [N,128]
    const float* __restrict__ mask,        // [N,1]
    const float* __restrict__ cent,        // [64,128]
    float* __restrict__ out,               // [64 + N*64]
    float* __restrict__ wcol,              // [64][nb] transposed column partials
    float* __restrict__ wmsk,              // [nb] mask partials
    int N, int nb, int atomicMode)
{
    __shared__ float sa[NPB * LDSROW];     // 16896 B node tile (padded rows)
    __shared__ float s_su[NPB];            // per-node ||u||^2
    __shared__ float s_ms[NPB];            // per-node mask (0 for OOB rows)

    const int tid  = threadIdx.x;
    const int lane = tid & 63;
    const int wv   = tid >> 6;
    const int quad = lane >> 4;            // 0..3 (k-slice)
    const int lm   = lane & 15;            // A row (cent) / B col (node)
    const int cw   = wv * 16;              // wave's centroid group base
    const int node0 = blockIdx.x * NPB;

    // ---- node staging: thread owns row tid>>3, 64B chunk (tid&7)*16 ----
    const int srow = tid >> 3;
    const int scol = (tid & 7) * 16;
    {
        int row = node0 + srow;
        int rc  = row < N ? row : N - 1;
        const float* p = node_repr + (long)rc * EMBED + scol;
        float4 r0 = *(const float4*)(p);
        float4 r1 = *(const float4*)(p + 4);
        float4 r2 = *(const float4*)(p + 8);
        float4 r3 = *(const float4*)(p + 12);
        float mrow = (row < N) ? mask[rc] : 0.f;

        float* dst = &sa[srow * LDSROW + scol];
        *(float4*)(dst)      = r0;
        *(float4*)(dst + 4)  = r1;
        *(float4*)(dst + 8)  = r2;
        *(float4*)(dst + 12) = r3;

        float pp = 0.f;
        pp = fmaf(r0.x,r0.x, fmaf(r0.y,r0.y, fmaf(r0.z,r0.z, fmaf(r0.w,r0.w, pp))));
        pp = fmaf(r1.x,r1.x, fmaf(r1.y,r1.y, fmaf(r1.z,r1.z, fmaf(r1.w,r1.w, pp))));
        pp = fmaf(r2.x,r2.x, fmaf(r2.y,r2.y, fmaf(r2.z,r2.z, fmaf(r2.w,r2.w, pp))));
        pp = fmaf(r3.x,r3.x, fmaf(r3.y,r3.y, fmaf(r3.z,r3.z, fmaf(r3.w,r3.w, pp))));
        pp += __shfl_xor(pp, 1); pp += __shfl_xor(pp, 2); pp += __shfl_xor(pp, 4);
        if ((tid & 7) == 0) { s_su[srow] = pp; s_ms[srow] = mrow; }
    }

    // ---- centroids (A): load + fp32 norm + bf16 pack, held in 16 VGPRs ----
    const float* ap = cent + (long)(cw + lm) * EMBED + quad * 8;
    float svp = 0.f;
    bf16x8 aa[4];
    #pragma unroll
    for (int ks = 0; ks < 4; ++ks) {
        float4 a0 = *(const float4*)(ap + ks * 32);
        float4 a1 = *(const float4*)(ap + ks * 32 + 4);
        svp = fmaf(a0.x,a0.x, fmaf(a0.y,a0.y, fmaf(a0.z,a0.z, fmaf(a0.w,a0.w, svp))));
        svp = fmaf(a1.x,a1.x, fmaf(a1.y,a1.y, fmaf(a1.z,a1.z, fmaf(a1.w,a1.w, svp))));
        aa[ks] = pack8(a0, a1);
    }
    svp += __shfl_xor(svp, 16); svp += __shfl_xor(svp, 32);   // full ||c||^2, cent cw+lm
    // redistribute to D-row mapping: lane needs cents cw+quad*4+r
    float svr[4], sv1r[4];
    #pragma unroll
    for (int r = 0; r < 4; ++r) {
        svr[r]  = __shfl(svp, quad * 4 + r);
        sv1r[r] = 1.f - svr[r];
    }

    __syncthreads();                       // node tile + s_su/s_ms visible

    // ---- MFMA: B (nodes) from LDS, same proven lm-row/quad-k pattern ----
    f32x4 acc0 = {0.f,0.f,0.f,0.f}, acc1 = {0.f,0.f,0.f,0.f};
    #pragma unroll
    for (int ks = 0; ks < 4; ++ks) {
        const int base = quad * 8 + ks * 32;
        float4 b00 = *(const float4*)&sa[lm * LDSROW + base];
        float4 b01 = *(const float4*)&sa[lm * LDSROW + base + 4];
        float4 b10 = *(const float4*)&sa[(16 + lm) * LDSROW + base];
        float4 b11 = *(const float4*)&sa[(16 + lm) * LDSROW + base + 4];
        acc0 = __builtin_amdgcn_mfma_f32_16x16x32_bf16(aa[ks], pack8(b00, b01), acc0, 0, 0, 0);
        acc1 = __builtin_amdgcn_mfma_f32_16x16x32_bf16(aa[ks], pack8(b10, b11), acc1, 0, 0, 0);
    }

    // ---- epilogue: D row = cent cw+quad*4+r, col = node lm / 16+lm ----
    const float su0 = s_su[lm],      su1 = s_su[16 + lm];
    const float mk0 = s_ms[lm],      mk1 = s_ms[16 + lm];
    const float o0  = 1.f - su0,     o1  = 1.f - su1;
    const int   n0  = node0 + lm,    n1  = node0 + 16 + lm;

    float v0a[4], v1a[4], g[4];
    #pragma unroll
    for (int r = 0; r < 4; ++r) {
        {
            float sq = fmaxf(su0 + svr[r] - 2.f * acc0[r], 0.f);
            float dn = fmaxf(o0 * sv1r[r], EPS);
            float tt = fmaxf(2.f * sq * __builtin_amdgcn_rcpf(dn), EPS);
            v0a[r] = __logf(1.f + tt + sqrtf(tt * (tt + 2.f))) * mk0;
        }
        {
            float sq = fmaxf(su1 + svr[r] - 2.f * acc1[r], 0.f);
            float dn = fmaxf(o1 * sv1r[r], EPS);
            float tt = fmaxf(2.f * sq * __builtin_amdgcn_rcpf(dn), EPS);
            v1a[r] = __logf(1.f + tt + sqrtf(tt * (tt + 2.f))) * mk1;
        }
        g[r] = v0a[r] + v1a[r];
    }
    // vector stores: 4 consecutive cents per lane, 16B aligned
    if (n0 < N) {
        float4 V0 = {v0a[0], v0a[1], v0a[2], v0a[3]};
        *(float4*)(out + NUM_C + (long)n0 * NUM_C + cw + quad * 4) = V0;
    }
    if (n1 < N) {
        float4 V1 = {v1a[0], v1a[1], v1a[2], v1a[3]};
        *(float4*)(out + NUM_C + (long)n1 * NUM_C + cw + quad * 4) = V1;
    }

    // ---- per-cent column sums over the tile's 32 nodes (in-quad reduce) ----
    #pragma unroll
    for (int r = 0; r < 4; ++r) {
        g[r] += __shfl_xor(g[r], 1);
        g[r] += __shfl_xor(g[r], 2);
        g[r] += __shfl_xor(g[r], 4);
        g[r] += __shfl_xor(g[r], 8);
    }
    if (lm == 0) {
        if (atomicMode) {
            #pragma unroll
            for (int r = 0; r < 4; ++r) atomicAdd(&wcol[cw + quad * 4 + r], g[r]);
        } else {
            #pragma unroll
            for (int r = 0; r < 4; ++r)
                wcol[(long)(cw + quad * 4 + r) * nb + blockIdx.x] = g[r];
        }
    }

    // ---- block mask partial (wave 0; s_ms complete after barrier) ----
    if (wv == 0) {
        float ms = (lane < NPB) ? s_ms[lane] : 0.f;
        #pragma unroll
        for (int k = 32; k; k >>= 1) ms += __shfl_xor(ms, k, 64);
        if (lane == 0) {
            if (atomicMode) atomicAdd(&wmsk[0], ms);
            else            wmsk[blockIdx.x] = ms;
        }
    }
}

// Reduce: 64 blocks; block c sums its contiguous column + (redundantly) mask.
__global__ __launch_bounds__(256) void cd_fin1(
    const float* __restrict__ wcol, const float* __restrict__ wmsk,
    float* __restrict__ out, int nb)
{
    __shared__ float rs[4], rm[4];
    const int c   = blockIdx.x;
    const int tid = threadIdx.x;

    float s = 0.f, m = 0.f;
    for (int b = tid; b < nb; b += 256) {
        s += wcol[(long)c * nb + b];        // coalesced: contiguous column
        m += wmsk[b];
    }
    #pragma unroll
    for (int k = 32; k; k >>= 1) { s += __shfl_xor(s, k, 64); m += __shfl_xor(m, k, 64); }
    if ((tid & 63) == 0) { rs[tid >> 6] = s; rm[tid >> 6] = m; }
    __syncthreads();
    if (tid == 0)
        out[c] = (rs[0] + rs[1] + rs[2] + rs[3]) / (rm[0] + rm[1] + rm[2] + rm[3]);
}

// atomic-mode fallback helpers
__global__ void cd_zero(float* acc) { if (threadIdx.x < NUM_C + 1) acc[threadIdx.x] = 0.f; }
__global__ void cd_fin_atomic(const float* __restrict__ acc, float* __restrict__ out) {
    int c = threadIdx.x;
    if (c < NUM_C) out[c] = acc[c] / acc[NUM_C];
}

extern "C" void kernel_launch(void* const* d_in, const int* in_sizes, int n_in,
                              void* d_out, int out_size, void* d_ws, size_t ws_size,
                              hipStream_t stream) {
    const float* node_repr = (const float*)d_in[0];
    const float* mask      = (const float*)d_in[1];
    const float* cent      = (const float*)d_in[2];
    float* out = (float*)d_out;

    const int N  = in_sizes[0] / EMBED;
    const int nb = (N + NPB - 1) / NPB;
    const size_t needed = ((size_t)NUM_C * nb + nb) * sizeof(float);

    if (ws_size >= needed) {
        float* wcol = (float*)d_ws;                  // [64][nb] transposed
        float* wmsk = wcol + (size_t)NUM_C * nb;     // [nb]
        cd_main<<<nb, 256, 0, stream>>>(node_repr, mask, cent, out, wcol, wmsk, N, nb, 0);
        cd_fin1<<<NUM_C, 256, 0, stream>>>(wcol, wmsk, out, nb);
    } else {
        float* acc = (float*)d_ws;   // 65 floats
        cd_zero<<<1, 128, 0, stream>>>(acc);
        cd_main<<<nb, 256, 0, stream>>>(node_repr, mask, cent, out, acc, acc + NUM_C, N, nb, 1);
        cd_fin_atomic<<<1, 64, 0, stream>>>(acc, out);
    }
}